// Round 12
// baseline (79.603 us; speedup 1.0000x reference)
//
#include <hip/hip_runtime.h>
#include <hip/hip_bf16.h>

// Problem constants
#define NN    32
#define CC    49
#define HWSZ  81
#define MSZ   24
#define KSZ   7
#define PADSZ 3
#define NHW   (NN*HWSZ)     // 2592
#define NCHW  (NN*CC*HWSZ)  // 127008

// LDS strides (in shorts / bf16 elements). All row strides * 2B are multiples
// of 16B (b128-aligned fragment loads) and chosen to stagger bank starts.
// Total LDS = 13312 + 13312 + 13824 + 9216 = 49664 B < 52 KB -> 3 blocks/CU,
// grid 768 = 256 CU x 3 -> fully resident in one round.
#define XSB_S  104   // xsb[64][104]  : x[n] as bf16 (pads zeroed surgically)
#define MSK_S  104   // msk[64][104]  : mask rows dd (pads zeroed surgically)
#define MSKT_S 72    // mskT[96][72]  : mask transposed (pads zeroed surgically)
#define G_S    72    // gm[64][72]    : leaky(fk)[c][dd]; wave-private rows

typedef __attribute__((ext_vector_type(8))) short short8;
typedef __attribute__((ext_vector_type(4))) short short4v;
typedef __attribute__((ext_vector_type(4))) float f32x4;

__device__ __forceinline__ short f2b(float v) {
    unsigned u = __float_as_uint(v);
    u += 0x7fffu + ((u >> 16) & 1u);      // round-to-nearest-even to bf16
    return (short)(u >> 16);
}
__device__ __forceinline__ float b2f(short s) {
    return __uint_as_float(((unsigned)(unsigned short)s) << 16);
}

// Kernel 1: one block (256 thr = 4 waves) per (n, o). TWO barriers only.
//   phase A: stage x->xsb + surgical pad zeros (disjoint writes); BARRIER
//   phase B: conv(K=7 over channel)+softmax(81, no max-sub: |logit|<=~13,
//            exp<=5e5, sum<=4e7, fp32-safe) from xsb; write msk/mskT; BARRIER
//   phase C: MFMA fk[c][dd] = xsb(c-rows) . msk(dd-rows)^T -> leaky ->
//            gm rows [16wv,16wv+16) — WAVE-PRIVATE (same rows read in D, so
//            no barrier; compiler orders same-wave LDS RAW via lgkmcnt)
//   phase D: MFMA out_partial[c][hw] = gm(64x64).mskT^T
//            use_ws=1: coalesced BF16 stores to bws[o][n][c][hw]
//            use_ws=0: fp32 atomicAdd into acc[n][c][hw] (fallback)
// Zero-pad map (every LDS word an MFMA reads is data or explicit 0):
//   xsb : rows 0-48 cols 81-95 + rows 49-63 cols 0-95 (phase C B.. A-frag K<=95)
//   msk : rows 0-48 cols 80-95 (col 80 later overwritten by B) + rows 49-63
//         cols 0-95  -> fk[c][dd>=49]=0 -> gm cols 49-63 = 0
//   mskT: rows 0-80 cols 48-63 (col 48 overwritten by B) + rows 81-95 cols 0-63
__global__ __launch_bounds__(256) void fuse_k1(
    const float* __restrict__ x, const float* __restrict__ cw,
    const float* __restrict__ cb, float* __restrict__ acc, int use_ws)
{
    __shared__ short xsb [64 * XSB_S];    // 13312 B
    __shared__ short msk [64 * MSK_S];    // 13312 B
    __shared__ short mskT[96 * MSKT_S];   // 13824 B
    __shared__ short gm  [64 * G_S];      //  9216 B

    const int o = blockIdx.x;          // 0..23
    const int n = blockIdx.y;          // 0..31
    const int t = threadIdx.x;
    const int lane = t & 63;
    const int wv = t >> 6;             // 0..3
    const int lr = lane & 15;
    const int lq = lane >> 4;          // quad index 0..3

    const float* xg = x + (size_t)n * CC * HWSZ;
    float wk[KSZ];
    #pragma unroll
    for (int k = 0; k < KSZ; ++k) wk[k] = cw[o * KSZ + k];
    const float bias = cb[o];

    // ---- phase A: all writes disjoint ----
    const f32x4 z4 = {0.f, 0.f, 0.f, 0.f};
    // (a) stage x[n] data into xsb rows 0-48, cols 0-80
    for (int i = t; i < CC * HWSZ; i += 256) {
        int c = i / HWSZ, hw = i - c * HWSZ;
        xsb[c * XSB_S + hw] = f2b(xg[i]);
    }
    // (b) xsb pad cols 81..103 of rows 0-48 (scalar 81-87, b128 88-103)
    if (t < CC) {
        short* row = xsb + t * XSB_S;
        #pragma unroll
        for (int cq = 81; cq < 88; ++cq) row[cq] = 0;
        *(f32x4*)(row + 88) = z4;
        *(f32x4*)(row + 96) = z4;
    }
    // (c) xsb rows 49-63 full zero (15 rows x 13 b128-groups)
    for (int j = t; j < 15 * 13; j += 256) {
        int rr = j / 13, cg = j - rr * 13;
        *(f32x4*)(xsb + (49 + rr) * XSB_S + cg * 8) = z4;
    }
    // (d) msk surgical zero: rows 0-48 cols 80-95 (2 b128) = items 0..97;
    //     rows 49-63 cols 0-95 (12 b128) = items 98..277
    for (int j = t; j < 98 + 180; j += 256) {
        if (j < 98) {
            int r = j >> 1, h = j & 1;
            *(f32x4*)(msk + r * MSK_S + 80 + h * 8) = z4;
        } else {
            int jj = j - 98;
            int r = jj / 12, cg = jj - r * 12;
            *(f32x4*)(msk + (49 + r) * MSK_S + cg * 8) = z4;
        }
    }
    // (e) mskT surgical zero: rows 0-80 cols 48-63 (2 b128) = items 0..161;
    //     rows 81-95 cols 0-63 (8 b128) = items 162..281
    for (int j = t; j < 162 + 120; j += 256) {
        if (j < 162) {
            int r = j >> 1, h = j & 1;
            *(f32x4*)(mskT + r * MSKT_S + 48 + h * 8) = z4;
        } else {
            int jj = j - 162;
            int r = jj >> 3, cg = jj & 7;
            *(f32x4*)(mskT + (81 + r) * MSKT_S + cg * 8) = z4;
        }
    }
    __syncthreads();

    // ---- phase B: conv + softmax (no max-sub); 4 rows per wave (row = lq).
    // Lane lr covers cols [4lr,4lr+4) (b64), col 64+lr, and col 80 on lr==0.
    #pragma unroll
    for (int it = 0; it < 4; ++it) {
        int dd = it * 16 + wv * 4 + lq;
        if (dd < CC) {
            float a0 = 0.f, a1 = 0.f, a2 = 0.f, a3 = 0.f, a4 = 0.f, a5 = 0.f;
            #pragma unroll
            for (int k = 0; k < KSZ; ++k) {
                int r = dd + k - PADSZ;
                if (r >= 0 && r < CC) {
                    const short* xr = xsb + r * XSB_S;
                    short4v xa = *(const short4v*)(xr + 4 * lr);
                    float w = wk[k];
                    a0 += w * b2f(xa[0]);
                    a1 += w * b2f(xa[1]);
                    a2 += w * b2f(xa[2]);
                    a3 += w * b2f(xa[3]);
                    a4 += w * b2f(xr[64 + lr]);
                    if (lr == 0) a5 += w * b2f(xr[80]);
                }
            }
            float e0 = __expf(a0 + bias), e1 = __expf(a1 + bias);
            float e2 = __expf(a2 + bias), e3 = __expf(a3 + bias);
            float e4 = __expf(a4 + bias);
            float e5 = (lr == 0) ? __expf(a5 + bias) : 0.f;
            float s = ((e0 + e1) + (e2 + e3)) + (e4 + e5);
            #pragma unroll
            for (int off = 8; off; off >>= 1) s += __shfl_xor(s, off, 64);
            float inv = __builtin_amdgcn_rcpf(s);
            short4v pk;
            pk[0] = f2b(e0 * inv); pk[1] = f2b(e1 * inv);
            pk[2] = f2b(e2 * inv); pk[3] = f2b(e3 * inv);
            short b4 = f2b(e4 * inv);
            short* mrow = msk + dd * MSK_S;
            *(short4v*)(mrow + 4 * lr) = pk;        // b64, 8B-aligned
            mrow[64 + lr] = b4;
            mskT[(4 * lr    ) * MSKT_S + dd] = pk[0];
            mskT[(4 * lr + 1) * MSKT_S + dd] = pk[1];
            mskT[(4 * lr + 2) * MSKT_S + dd] = pk[2];
            mskT[(4 * lr + 3) * MSKT_S + dd] = pk[3];
            mskT[(64 + lr   ) * MSKT_S + dd] = b4;
            if (lr == 0) {
                short b5 = f2b(e5 * inv);
                mrow[80] = b5;
                mskT[80 * MSKT_S + dd] = b5;
            }
        }
    }
    __syncthreads();

    // ---- phase C (MFMA): fk[c][dd] = sum_hw xsb[c][hw] * msk[dd][hw]
    // M=c (ONE tile per wave: rows 16wv..16wv+15), N=dd (4 tiles), K=hw (96).
    // Wave-private gm rows -> no barrier before phase D.
    {
        short8 ax[3];
        #pragma unroll
        for (int ks = 0; ks < 3; ++ks)
            ax[ks] = *(const short8*)&xsb[(wv * 16 + lr) * XSB_S + ks * 32 + lq * 8];
        #pragma unroll
        for (int nt = 0; nt < 4; ++nt) {
            f32x4 accv = {0.f, 0.f, 0.f, 0.f};
            #pragma unroll
            for (int ks = 0; ks < 3; ++ks) {
                short8 b = *(const short8*)&msk[(nt * 16 + lr) * MSK_S + ks * 32 + lq * 8];
                accv = __builtin_amdgcn_mfma_f32_16x16x32_bf16(ax[ks], b, accv, 0, 0, 0);
            }
            // C-layout: lane holds fk[c = wv*16 + lq*4 + r][dd = nt*16 + lr]
            #pragma unroll
            for (int r = 0; r < 4; ++r) {
                float v = accv[r];
                v = (v >= 0.f) ? v : 0.01f * v;
                gm[(wv * 16 + lq * 4 + r) * G_S + nt * 16 + lr] = f2b(v);
            }
        }
    }
    // no __syncthreads(): phase D reads only gm rows written by this wave;
    // compiler inserts lgkmcnt waits for the same-wave LDS RAW.

    // ---- phase D (MFMA): out_partial[c][hw] = sum_dd gm[c][dd] * mskT[hw][dd]
    // M=c (4 tiles, one per wave), N=hw (6 tiles), K=dd (64, 2 steps).
    {
        short* bws = (short*)acc + (size_t)(o * NN + n) * CC * HWSZ;  // bf16 ws
        float* dstn = acc + (size_t)n * CC * HWSZ;                    // fallback
        short8 a1[2];
        #pragma unroll
        for (int ks = 0; ks < 2; ++ks)
            a1[ks] = *(const short8*)&gm[(wv * 16 + lr) * G_S + ks * 32 + lq * 8];
        #pragma unroll
        for (int nt = 0; nt < 6; ++nt) {
            f32x4 accv = {0.f, 0.f, 0.f, 0.f};
            #pragma unroll
            for (int ks = 0; ks < 2; ++ks) {
                short8 b = *(const short8*)&mskT[(nt * 16 + lr) * MSKT_S + ks * 32 + lq * 8];
                accv = __builtin_amdgcn_mfma_f32_16x16x32_bf16(a1[ks], b, accv, 0, 0, 0);
            }
            int hw = nt * 16 + lr;
            if (hw < HWSZ) {
                int cb = wv * 16 + lq * 4;
                if (use_ws) {
                    #pragma unroll
                    for (int r = 0; r < 4; ++r) {
                        int c = cb + r;
                        if (c < CC) bws[c * HWSZ + hw] = f2b(accv[r]);
                    }
                } else {
                    #pragma unroll
                    for (int r = 0; r < 4; ++r) {
                        int c = cb + r;
                        if (c < CC) atomicAdd(dstn + c * HWSZ + hw, accv[r]);
                    }
                }
            }
        }
    }
}

// Kernel 2 (ws path): one block per channel c (1024 thr). Sums the 24 per-o
// bf16 partials (4 independent fp32 accumulators for MLP) + fp32 residual,
// batch-norm over (N,H,W), writes d_out.
__global__ __launch_bounds__(1024) void fuse_k2w(
    const short* __restrict__ bws, const float* __restrict__ x,
    const float* __restrict__ gamma, const float* __restrict__ beta,
    float* __restrict__ out)
{
    const int c = blockIdx.x;
    const int t = threadIdx.x;
    float vals[3];
    float sum = 0.f, sq = 0.f;
    int cnt = 0;
    for (int i = t; i < NHW; i += 1024) {
        int n = i / HWSZ;
        int hw = i - n * HWSZ;
        int idx = (n * CC + c) * HWSZ + hw;
        const short* p = bws + idx;
        float v0 = x[idx], v1 = 0.f, v2 = 0.f, v3 = 0.f;
        #pragma unroll
        for (int o = 0; o < MSZ; o += 4) {
            v0 += b2f(p[(size_t)(o    ) * NCHW]);
            v1 += b2f(p[(size_t)(o + 1) * NCHW]);
            v2 += b2f(p[(size_t)(o + 2) * NCHW]);
            v3 += b2f(p[(size_t)(o + 3) * NCHW]);
        }
        float v = (v0 + v1) + (v2 + v3);
        vals[cnt++] = v;
        sum += v; sq += v * v;
    }
    #pragma unroll
    for (int off = 32; off; off >>= 1) {
        sum += __shfl_xor(sum, off, 64);
        sq  += __shfl_xor(sq, off, 64);
    }
    __shared__ float rs[16], rq[16];
    const int lane = t & 63, wv = t >> 6;
    if (lane == 0) { rs[wv] = sum; rq[wv] = sq; }
    __syncthreads();
    float ts = 0.f, tq = 0.f;
    #pragma unroll
    for (int w = 0; w < 16; ++w) { ts += rs[w]; tq += rq[w]; }
    const float invD = 1.f / (float)NHW;
    float mean = ts * invD;
    float var  = tq * invD - mean * mean;
    float scal = rsqrtf(var + 1e-5f) * gamma[c];
    float shft = beta[c] - mean * scal;
    cnt = 0;
    for (int i = t; i < NHW; i += 1024) {
        int n = i / HWSZ;
        int hw = i - n * HWSZ;
        out[(n * CC + c) * HWSZ + hw] = vals[cnt++] * scal + shft;
    }
}

// Kernel 2 (fallback, atomic path): residual add + batch-norm in-place on d_out.
__global__ __launch_bounds__(1024) void fuse_k2(
    float* __restrict__ out, const float* __restrict__ x,
    const float* __restrict__ gamma, const float* __restrict__ beta)
{
    const int c = blockIdx.x;
    const int t = threadIdx.x;
    float vals[3];
    float sum = 0.f, sq = 0.f;
    int cnt = 0;
    for (int i = t; i < NHW; i += 1024) {
        int n = i / HWSZ;
        int hw = i - n * HWSZ;
        int idx = (n * CC + c) * HWSZ + hw;
        float v = out[idx] + x[idx];
        vals[cnt++] = v;
        sum += v; sq += v * v;
    }
    #pragma unroll
    for (int off = 32; off; off >>= 1) {
        sum += __shfl_xor(sum, off, 64);
        sq  += __shfl_xor(sq, off, 64);
    }
    __shared__ float rs[16], rq[16];
    const int lane = t & 63, wv = t >> 6;
    if (lane == 0) { rs[wv] = sum; rq[wv] = sq; }
    __syncthreads();
    float ts = 0.f, tq = 0.f;
    #pragma unroll
    for (int w = 0; w < 16; ++w) { ts += rs[w]; tq += rq[w]; }
    const float invD = 1.f / (float)NHW;
    float mean = ts * invD;
    float var  = tq * invD - mean * mean;
    float scal = rsqrtf(var + 1e-5f) * gamma[c];
    float shft = beta[c] - mean * scal;
    cnt = 0;
    for (int i = t; i < NHW; i += 1024) {
        int n = i / HWSZ;
        int hw = i - n * HWSZ;
        out[(n * CC + c) * HWSZ + hw] = vals[cnt++] * scal + shft;
    }
}

extern "C" void kernel_launch(void* const* d_in, const int* in_sizes, int n_in,
                              void* d_out, int out_size, void* d_ws, size_t ws_size,
                              hipStream_t stream) {
    const float* x     = (const float*)d_in[0];
    const float* cw    = (const float*)d_in[1];
    const float* cb    = (const float*)d_in[2];
    const float* gamma = (const float*)d_in[3];
    const float* beta  = (const float*)d_in[4];
    float* out = (float*)d_out;

    const size_t need = (size_t)MSZ * NCHW * sizeof(short);   // 6.1 MB (bf16)
    if (ws_size >= need) {
        fuse_k1<<<dim3(MSZ, NN), 256, 0, stream>>>(x, cw, cb, (float*)d_ws, 1);
        fuse_k2w<<<CC, 1024, 0, stream>>>((const short*)d_ws, x, gamma, beta, out);
    } else {
        hipMemsetAsync(out, 0, (size_t)NCHW * sizeof(float), stream);
        fuse_k1<<<dim3(MSZ, NN), 256, 0, stream>>>(x, cw, cb, out, 0);
        fuse_k2<<<CC, 1024, 0, stream>>>(out, x, gamma, beta);
    }
}